// Round 15
// baseline (125.943 us; speedup 1.0000x reference)
//
#include <hip/hip_runtime.h>
#include <hip/hip_bf16.h>
#include <math.h>

typedef short bf16x8 __attribute__((ext_vector_type(8)));   // 8 bf16 in 4 VGPRs
typedef float f32x16 __attribute__((ext_vector_type(16)));  // 32x32 MFMA acc

#define NB 8192
#define ND 256
#define NCLSR 100         // label values 0..99
#define BK 64             // K-chunk staged in LDS per iteration
#define INV_T 20.0f       // 1/TEMPERATURE
#define LOG2E_T 28.853900817779268f   // 20*log2(e): exp(20x) = 2^(x*this)
#define HI_THR 1.2026042e6f           // exp(14)
#define SELF_TERM 4.85165195e8f       // exp(20)

// scal[] layout: [0]=possum [1]=SL [2]=RL [3]=NH [4]=NT [5]=done-counter(int)

// ---------------- Kernel 1: row L2-normalize -> bf16 copy; zero accumulators --------
__global__ __launch_bounds__(256) void normalize_kernel(
    const float* __restrict__ feat, unsigned short* __restrict__ fb,
    float* __restrict__ hsum, float* __restrict__ nhighf,
    float* __restrict__ scal) {
    const int wave = threadIdx.x >> 6;
    const int lane = threadIdx.x & 63;
    const int row  = blockIdx.x * 4 + wave;
    float4 v = reinterpret_cast<const float4*>(feat + (size_t)row * ND)[lane];
    float ss = v.x * v.x + v.y * v.y + v.z * v.z + v.w * v.w;
    #pragma unroll
    for (int off = 32; off > 0; off >>= 1) ss += __shfl_xor(ss, off);
    const float inv = rsqrtf(ss);
    ushort4 o;
    __hip_bfloat16 h0 = __float2bfloat16(v.x * inv); o.x = *reinterpret_cast<unsigned short*>(&h0);
    __hip_bfloat16 h1 = __float2bfloat16(v.y * inv); o.y = *reinterpret_cast<unsigned short*>(&h1);
    __hip_bfloat16 h2 = __float2bfloat16(v.z * inv); o.z = *reinterpret_cast<unsigned short*>(&h2);
    __hip_bfloat16 h3 = __float2bfloat16(v.w * inv); o.w = *reinterpret_cast<unsigned short*>(&h3);
    reinterpret_cast<ushort4*>(fb + (size_t)row * ND)[lane] = o;
    if (blockIdx.x < 32) {
        const int i = (blockIdx.x << 8) + threadIdx.x;
        hsum[i] = 0.f;
        nhighf[i] = 0.f;
    } else if (blockIdx.x == 32 && threadIdx.x < 6) {
        scal[threadIdx.x] = 0.f;           // int 0 == float 0 bit pattern
    }
}

// ---------------- Kernel 2: TRIANGULAR sim tiles, dual-MFMA (acc + acc^T) ----------
// R15 vs R14: the K-loop also accumulates accT = MFMA(b,a) (same fragments,
// swapped operands -> E^T at zero extra ds_read cost). accT's lane axis is the
// I-row, so ROW sums become free in-register reductions (like col sums from
// acc). The whole E-through-LDS apparatus (64 ds_write_b16/lane, pass-2 MFMA
// ones-trick, 2 barriers, bf16 rounding) is deleted; the extra 64 MFMA/wave
// land on the 15%-busy matrix pipe. Row sums now full fp32.
// acc 128 f32 (unified AGPR) + 16 frag regs fits (256,2)'s 256-reg cap ->
// 2 blocks/CU co-resident, no spill.
__global__ __launch_bounds__(256, 2) void sim_kernel(
    const unsigned short* __restrict__ fb, const int* __restrict__ labels,
    float* __restrict__ Q, float* __restrict__ hsum,
    float* __restrict__ nhighf, float* __restrict__ scal) {
    __shared__ __align__(16) unsigned short ldsA[128 * BK];   // 16 KB
    __shared__ __align__(16) unsigned short ldsB[128 * BK];   // 16 KB
    __shared__ float ldsRow[2][128];       // [wx][local row] partial row sums
    __shared__ float ldsCol[2][128];       // [wy][local col] partial col sums
    __shared__ int   ldsLab[256];          // [0..127]=row labels, [128..255]=col labels
    __shared__ float ldsP[4];              // per-wave possum partials

    // triangular decode: t -> (bi, bj), bi >= bj  (validated R5-R14)
    const int t = blockIdx.x;
    int bi = (int)((sqrtf((float)(8 * t + 1)) - 1.0f) * 0.5f);
    while ((bi + 1) * (bi + 2) / 2 <= t) ++bi;
    while (bi * (bi + 1) / 2 > t) --bi;
    const int bj = t - bi * (bi + 1) / 2;
    const int I0 = bi << 7;
    const int J0 = bj << 7;
    const bool isdiag = (bi == bj);

    const int tid  = threadIdx.x;
    const int wave = tid >> 6;             // 0..3
    const int lane = tid & 63;
    const int wy = wave >> 1;              // 0..1 : row half (64 rows)
    const int wx = wave & 1;               // 0..1 : col half (64 cols)
    const int l31  = lane & 31;
    const int half = lane >> 5;

    if (tid < 128) ldsLab[tid] = labels[I0 + tid];
    else           ldsLab[tid] = labels[J0 + tid - 128];

    // staging: wave stages rows [32w,+32); chunk c: Lg=(c<<6)+lane,
    // row_loc = 32w + (Lg>>3), granule g = (Lg&7)^((Lg>>3)&7)  (R4-validated)
    int offRC[4];
    #pragma unroll
    for (int c = 0; c < 4; ++c) {
        const int Lg = (c << 6) + lane;
        const int row_loc = (wave << 5) + (Lg >> 3);
        const int g = (Lg & 7) ^ ((Lg >> 3) & 7);
        offRC[c] = row_loc * ND + (g << 3);
    }
    const unsigned short* baseA = fb + (size_t)I0 * ND;
    const unsigned short* baseB = fb + (size_t)J0 * ND;

    f32x16 acc[2][2];                      // acc[fy][fx]: D[m=I-row band][n], lane n = I... (col = J)
    f32x16 accT[2][2];                     // accT[fx][fy]: lane n = I-row, regs m = J-col band
    #pragma unroll
    for (int fy = 0; fy < 2; ++fy)
        #pragma unroll
        for (int fx = 0; fx < 2; ++fx)
            #pragma unroll
            for (int e = 0; e < 16; ++e) { acc[fy][fx][e] = 0.f; accT[fx][fy][e] = 0.f; }

    for (int kk = 0; kk < ND; kk += BK) {
        __syncthreads();                   // protect LDS from prior-iter readers
        #pragma unroll
        for (int c = 0; c < 4; ++c) {
            __builtin_amdgcn_global_load_lds(
                (const __attribute__((address_space(1))) void*)(baseA + offRC[c] + kk),
                (__attribute__((address_space(3))) void*)(ldsA + (wave << 11) + (c << 9)),
                16, 0, 0);
            __builtin_amdgcn_global_load_lds(
                (const __attribute__((address_space(1))) void*)(baseB + offRC[c] + kk),
                (__attribute__((address_space(3))) void*)(ldsB + (wave << 11) + (c << 9)),
                16, 0, 0);
        }
        __syncthreads();                   // staging visible

        #pragma unroll
        for (int s = 0; s < 4; ++s) {      // four k-steps of 16 within BK=64
            const int gp = ((s << 1) + half) ^ (l31 & 7);
            bf16x8 a[2], b[2];
            #pragma unroll
            for (int f = 0; f < 2; ++f) {
                const int rowA = (wy << 6) + (f << 5) + l31;
                const int rowB = (wx << 6) + (f << 5) + l31;
                a[f] = *reinterpret_cast<const bf16x8*>(ldsA + rowA * BK + (gp << 3));
                b[f] = *reinterpret_cast<const bf16x8*>(ldsB + rowB * BK + (gp << 3));
            }
            #pragma unroll
            for (int fy = 0; fy < 2; ++fy)
                #pragma unroll
                for (int fx = 0; fx < 2; ++fx) {
                    acc[fy][fx]  = __builtin_amdgcn_mfma_f32_32x32x16_bf16(
                        a[fy], b[fx], acc[fy][fx], 0, 0, 0);
                    accT[fx][fy] = __builtin_amdgcn_mfma_f32_32x32x16_bf16(
                        b[fx], a[fy], accT[fx][fy], 0, 0, 0);
                }
        }
    }

    // Epilogue. C/D layout (m74/m101-verified): col = l31, row = (reg&3)+8*(reg>>2)+4*half.
    // acc[fy][fx]: lane = J-col (wx*64+fx*32+l31), regs = I-rows  -> col sums + pp + anyhigh
    // accT[fx][fy]: lane = I-row (wy*64+fy*32+l31), regs = J-cols -> row sums (no labels needed)
    int ccol[2], lcol[2];
    #pragma unroll
    for (int fx = 0; fx < 2; ++fx) {
        ccol[fx] = (wx << 6) + (fx << 5) + l31;
        lcol[fx] = ldsLab[128 + ccol[fx]];
    }

    float cs[2] = {0.f, 0.f};              // col partials (this lane's 2 cols)
    float rs[2] = {0.f, 0.f};              // row partials (this lane's 2 rows)
    float pp = 0.f;

    if (!isdiag) {                         // lean path (2016 blocks)
        #pragma unroll
        for (int fy = 0; fy < 2; ++fy) {
            const int rbase = (wy << 6) + (fy << 5) + (half << 2);
            int4 lr[4];
            #pragma unroll
            for (int g = 0; g < 4; ++g)
                lr[g] = *reinterpret_cast<const int4*>(&ldsLab[rbase + (g << 3)]);
            #pragma unroll
            for (int reg = 0; reg < 16; ++reg) {
                const int g = reg >> 2, idx = reg & 3;
                const int lrow = (idx == 0) ? lr[g].x : (idx == 1) ? lr[g].y
                               : (idx == 2) ? lr[g].z : lr[g].w;
                #pragma unroll
                for (int fx = 0; fx < 2; ++fx) {
                    const float av = acc[fy][fx][reg];
                    cs[fx] += exp2f(av * LOG2E_T);
                    if (lcol[fx] == lrow) pp += av;
                    rs[fy] += exp2f(accT[fx][fy][reg] * LOG2E_T);
                }
            }
        }
    } else {                               // careful path (64 diag blocks)
        #pragma unroll
        for (int fy = 0; fy < 2; ++fy) {
            #pragma unroll
            for (int reg = 0; reg < 16; ++reg) {
                const int rloc = (reg & 3) + ((reg >> 2) << 3) + (half << 2);
                const int row_local = (wy << 6) + (fy << 5) + rloc;
                const int lrow = ldsLab[row_local];
                #pragma unroll
                for (int fx = 0; fx < 2; ++fx) {
                    const bool dband = (((wy << 1) + fy) == ((wx << 1) + fx));
                    const bool diag_el = dband && (l31 == rloc);
                    const float av = acc[fy][fx][reg];
                    float e = exp2f(av * LOG2E_T);
                    if (diag_el) e = 0.f;
                    cs[fx] += e;
                    if (lcol[fx] == lrow && !diag_el) pp += av;
                    float eT = exp2f(accT[fx][fy][reg] * LOG2E_T);
                    if (diag_el) eT = 0.f;  // same (fy,fx,reg,l31) marks the transposed diag
                    rs[fy] += eT;
                }
            }
        }
    }
    const int anyhigh = (cs[0] > HI_THR) || (cs[1] > HI_THR);  // no false negatives
    #pragma unroll
    for (int f = 0; f < 2; ++f) {
        cs[f] += __shfl_xor(cs[f], 32);    // combine halves (same col)
        rs[f] += __shfl_xor(rs[f], 32);    // combine halves (same row)
    }
    if (half == 0) {
        ldsCol[wy][ccol[0]] = cs[0];
        ldsCol[wy][ccol[1]] = cs[1];
        ldsRow[wx][(wy << 6) + l31]      = rs[0];
        ldsRow[wx][(wy << 6) + 32 + l31] = rs[1];
    }
    #pragma unroll
    for (int off = 32; off > 0; off >>= 1) pp += __shfl_xor(pp, off);
    if (lane == 0) ldsP[wave] = pp;

    // Cold path (never taken for this data): relax-term bookkeeping.
    if (__any(anyhigh)) {
        #pragma unroll
        for (int fy = 0; fy < 2; ++fy) {
            #pragma unroll
            for (int reg = 0; reg < 16; ++reg) {
                const int rloc = (reg & 3) + ((reg >> 2) << 3) + (half << 2);
                const int row_local = (wy << 6) + (fy << 5) + rloc;
                const int lrow = ldsLab[row_local];
                #pragma unroll
                for (int fx = 0; fx < 2; ++fx) {
                    const bool dband = isdiag && (((wy << 1) + fy) == ((wx << 1) + fx));
                    const bool diag_el = dband && (l31 == rloc);
                    const float av = acc[fy][fx][reg];
                    if (av > 0.7f && lcol[fx] == lrow && !diag_el) {
                        const float e2 = exp2f(av * LOG2E_T);
                        atomicAdd(&hsum[I0 + row_local], e2);
                        atomicAdd(&nhighf[I0 + row_local], 1.f);
                        if (!isdiag) {
                            atomicAdd(&hsum[J0 + ccol[fx]], e2);
                            atomicAdd(&nhighf[J0 + ccol[fx]], 1.f);
                        }
                    }
                }
            }
        }
    }
    __syncthreads();                       // ldsRow/ldsCol/ldsP complete

    if (tid < 128) {
        Q[(size_t)(bi * 64 + bj) * 128 + tid] = ldsRow[0][tid] + ldsRow[1][tid];
    } else if (!isdiag) {
        const int c2 = tid - 128;
        Q[(size_t)(bj * 64 + bi) * 128 + c2] = ldsCol[0][c2] + ldsCol[1][c2];
    }
    if (tid == 0) {
        const float scale = isdiag ? 1.f : 2.f;
        atomicAdd(&scal[0], (ldsP[0] + ldsP[1] + ldsP[2] + ldsP[3]) * scale);
    }
}

// ---------------- Kernel 3: fused Q-reduce + finalize (64 blocks) ----------------
__global__ __launch_bounds__(256) void finalize_kernel(
    const float* __restrict__ Q, const float* __restrict__ hsum,
    const float* __restrict__ nhighf, const int* __restrict__ labels,
    float* __restrict__ scal, float* __restrict__ out) {
    const int g = blockIdx.x;
    const int tid = threadIdx.x;
    __shared__ int cnt[128];
    if (tid < 128) cnt[tid] = 0;
    __syncthreads();
    for (int i = tid; i < NB; i += 256)
        atomicAdd(&cnt[labels[i]], 1);
    const int r = tid & 127;
    const int sh = tid >> 7;
    const float* base = Q + (size_t)g * 64 * 128;
    float s = 0.f;
    #pragma unroll 8
    for (int i = 0; i < 32; ++i)
        s += base[(size_t)(sh * 32 + i) * 128 + r];
    __shared__ float red[256];
    red[tid] = s;
    __syncthreads();
    float SL = 0.f, RL = 0.f, NH = 0.f, NT = 0.f;
    if (tid < 128) {
        const float denom = red[tid] + red[tid + 128];
        const int i = (g << 7) + tid;
        const float np = (float)(cnt[labels[i]] - 1);
        SL = np * logf(denom + 1e-8f);
        const float h = hsum[i];
        if (h > 0.f) RL = logf(h + SELF_TERM);
        NH = nhighf[i];
    }
    if (g == 0 && tid < NCLSR) {
        const float nc = (float)cnt[tid];
        NT = nc * (nc - 1.f);
    }
    #pragma unroll
    for (int off = 32; off > 0; off >>= 1) {
        SL += __shfl_xor(SL, off); RL += __shfl_xor(RL, off);
        NH += __shfl_xor(NH, off); NT += __shfl_xor(NT, off);
    }
    __shared__ float part[4][4];
    if ((tid & 63) == 0) {
        int w = tid >> 6;
        part[w][0] = SL; part[w][1] = RL; part[w][2] = NH; part[w][3] = NT;
    }
    __syncthreads();
    if (tid == 0) {
        float sl = part[0][0] + part[1][0] + part[2][0] + part[3][0];
        float rl = part[0][1] + part[1][1] + part[2][1] + part[3][1];
        float nh = part[0][2] + part[1][2] + part[2][2] + part[3][2];
        float nt = part[0][3] + part[1][3] + part[2][3] + part[3][3];
        atomicAdd(&scal[1], sl);
        atomicAdd(&scal[2], rl);
        atomicAdd(&scal[3], nh);
        if (g == 0) atomicAdd(&scal[4], nt);
        __threadfence();
        const int ticket = atomicAdd((int*)(scal + 5), 1);
        if (ticket == 63) {
            const float SLt = atomicAdd(&scal[1], 0.f);
            const float RLt = atomicAdd(&scal[2], 0.f);
            const float NHt = atomicAdd(&scal[3], 0.f);
            const float NTt = atomicAdd(&scal[4], 0.f);
            const float pos = atomicAdd(&scal[0], 0.f) * INV_T;
            const float scl   = (NTt > 0.f) ? (SLt - pos) / NTt : 0.f;
            const float relax = (NHt > 0.f) ? RLt / NHt : 0.f;
            out[0] = scl + relax;
        }
    }
}

extern "C" void kernel_launch(void* const* d_in, const int* in_sizes, int n_in,
                              void* d_out, int out_size, void* d_ws, size_t ws_size,
                              hipStream_t stream) {
    const float* feat  = (const float*)d_in[0];
    const int* labels  = (const int*)d_in[1];
    float* out = (float*)d_out;

    char* ws = (char*)d_ws;
    unsigned short* fb = (unsigned short*)ws;                                // 4 MB
    float* Q      = (float*)(ws + (size_t)NB * ND * sizeof(unsigned short)); // 2 MB
    float* hsum   = Q + 64 * 64 * 128;
    float* nhighf = hsum + NB;
    float* scal   = nhighf + NB;          // 6 floats: possum,SL,RL,NH,NT,done

    normalize_kernel<<<NB / 4, 256, 0, stream>>>(feat, fb, hsum, nhighf, scal);
    sim_kernel<<<2080, 256, 0, stream>>>(fb, labels, Q, hsum, nhighf, scal);
    finalize_kernel<<<64, 256, 0, stream>>>(Q, hsum, nhighf, labels, scal, out);
}

// Round 16
// 118.376 us; speedup vs baseline: 1.0639x; 1.0639x over previous
//
#include <hip/hip_runtime.h>
#include <hip/hip_bf16.h>
#include <math.h>

typedef short bf16x8 __attribute__((ext_vector_type(8)));   // 8 bf16 in 4 VGPRs
typedef float f32x16 __attribute__((ext_vector_type(16)));  // 32x32 MFMA acc

#define NB 8192
#define ND 256
#define NCLSR 100         // label values 0..99
#define BK 128            // K-chunk staged per round (R16: both 64-chunks at once)
#define ES 136            // padded E row stride (bf16): 272 B -> 16B-aligned rows
#define INV_T 20.0f       // 1/TEMPERATURE
#define LOG2E_T 28.853900817779268f   // 20*log2(e): exp(20x) = 2^(x*this)
#define HI_THR 1.2026042e6f           // exp(14)
#define SELF_TERM 4.85165195e8f       // exp(20)

// scal[] layout: [0]=possum [1]=SL [2]=RL [3]=NH [4]=NT [5]=done-counter(int)

// ---------------- Kernel 1: row L2-normalize -> bf16 copy; zero accumulators --------
__global__ __launch_bounds__(256) void normalize_kernel(
    const float* __restrict__ feat, unsigned short* __restrict__ fb,
    float* __restrict__ hsum, float* __restrict__ nhighf,
    float* __restrict__ scal) {
    const int wave = threadIdx.x >> 6;
    const int lane = threadIdx.x & 63;
    const int row  = blockIdx.x * 4 + wave;
    float4 v = reinterpret_cast<const float4*>(feat + (size_t)row * ND)[lane];
    float ss = v.x * v.x + v.y * v.y + v.z * v.z + v.w * v.w;
    #pragma unroll
    for (int off = 32; off > 0; off >>= 1) ss += __shfl_xor(ss, off);
    const float inv = rsqrtf(ss);
    ushort4 o;
    __hip_bfloat16 h0 = __float2bfloat16(v.x * inv); o.x = *reinterpret_cast<unsigned short*>(&h0);
    __hip_bfloat16 h1 = __float2bfloat16(v.y * inv); o.y = *reinterpret_cast<unsigned short*>(&h1);
    __hip_bfloat16 h2 = __float2bfloat16(v.z * inv); o.z = *reinterpret_cast<unsigned short*>(&h2);
    __hip_bfloat16 h3 = __float2bfloat16(v.w * inv); o.w = *reinterpret_cast<unsigned short*>(&h3);
    reinterpret_cast<ushort4*>(fb + (size_t)row * ND)[lane] = o;
    if (blockIdx.x < 32) {
        const int i = (blockIdx.x << 8) + threadIdx.x;
        hsum[i] = 0.f;
        nhighf[i] = 0.f;
    } else if (blockIdx.x == 32 && threadIdx.x < 6) {
        scal[threadIdx.x] = 0.f;           // int 0 == float 0 bit pattern
    }
}

// ---------------- Kernel 2: TRIANGULAR sim tiles, 4 waves x (64x64), BK=128 ----------
// R16 = R14 (best: 47.4 us) with BOTH K-chunks staged per round: 4 barriers/tile
// instead of 8 (each barrier is a full vmcnt-drain). LDS: 64 KB staging (+1.6 KB)
// -> still 2 blocks/CU (132 < 160 KB), registers identical to R14 (76+64, no
// spill). ds_read/MFMA counts unchanged. Swizzle: 16 granules/row, phys slot
// p in row r holds global granule p^(r&7); reader fetches ((s<<1)+half)^(l31&7).
// Padded-E MFMA row-sum trick, Q mirror slots, lean/diag split per R12/R14.
__global__ __launch_bounds__(256, 2) void sim_kernel(
    const unsigned short* __restrict__ fb, const int* __restrict__ labels,
    float* __restrict__ Q, float* __restrict__ hsum,
    float* __restrict__ nhighf, float* __restrict__ scal) {
    __shared__ __align__(16) unsigned short ldsU[2 * 128 * BK]; // 64 KB: A|B staging; E overlays
    __shared__ float ldsCol[2][128];       // [wy][local col] partial col sums
    __shared__ float ldsRowF[128];         // full row sums (MFMA ones-trick)
    __shared__ int   ldsLab[256];          // [0..127]=row labels, [128..255]=col labels
    __shared__ float ldsP[4];              // per-wave possum partials
    unsigned short* ldsA = ldsU;
    unsigned short* ldsB = ldsU + 128 * BK;
    unsigned short* ldsE = ldsU;           // 128 x ES bf16 overlay (34.8 KB < 64 KB)

    // triangular decode: t -> (bi, bj), bi >= bj  (validated R5-R14)
    const int t = blockIdx.x;
    int bi = (int)((sqrtf((float)(8 * t + 1)) - 1.0f) * 0.5f);
    while ((bi + 1) * (bi + 2) / 2 <= t) ++bi;
    while (bi * (bi + 1) / 2 > t) --bi;
    const int bj = t - bi * (bi + 1) / 2;
    const int I0 = bi << 7;
    const int J0 = bj << 7;
    const bool isdiag = (bi == bj);

    const int tid  = threadIdx.x;
    const int wave = tid >> 6;             // 0..3
    const int lane = tid & 63;
    const int wy = wave >> 1;              // 0..1 : row half (64 rows)
    const int wx = wave & 1;               // 0..1 : col half (64 cols)
    const int l31  = lane & 31;
    const int half = lane >> 5;

    if (tid < 128) ldsLab[tid] = labels[I0 + tid];
    else           ldsLab[tid] = labels[J0 + tid - 128];

    // staging: wave stages rows [32w,+32) x 128 cols; chunk c=0..7: Lg=(c<<6)+lane,
    // row_loc = 32w + (Lg>>4), granule g = (Lg&15)^((Lg>>4)&7)
    // (slot algebra: (c<<9)+(lane<<3) == (Lg>>4)*128 + (Lg&15)*8 == 8*Lg, checked)
    int offRC[8];
    #pragma unroll
    for (int c = 0; c < 8; ++c) {
        const int Lg = (c << 6) + lane;
        const int row_loc = (wave << 5) + (Lg >> 4);
        const int g = (Lg & 15) ^ ((Lg >> 4) & 7);
        offRC[c] = row_loc * ND + (g << 3);
    }
    const unsigned short* baseA = fb + (size_t)I0 * ND;
    const unsigned short* baseB = fb + (size_t)J0 * ND;

    f32x16 acc[2][2];
    #pragma unroll
    for (int fy = 0; fy < 2; ++fy)
        #pragma unroll
        for (int fx = 0; fx < 2; ++fx)
            #pragma unroll
            for (int e = 0; e < 16; ++e) acc[fy][fx][e] = 0.f;

    #pragma unroll
    for (int kk = 0; kk < ND; kk += BK) {  // two rounds of 128
        __syncthreads();                   // protect LDS from prior-round readers
        #pragma unroll
        for (int c = 0; c < 8; ++c) {
            __builtin_amdgcn_global_load_lds(
                (const __attribute__((address_space(1))) void*)(baseA + offRC[c] + kk),
                (__attribute__((address_space(3))) void*)(ldsA + (wave << 12) + (c << 9)),
                16, 0, 0);
            __builtin_amdgcn_global_load_lds(
                (const __attribute__((address_space(1))) void*)(baseB + offRC[c] + kk),
                (__attribute__((address_space(3))) void*)(ldsB + (wave << 12) + (c << 9)),
                16, 0, 0);
        }
        __syncthreads();                   // staging visible

        #pragma unroll
        for (int s = 0; s < 8; ++s) {      // eight k-steps of 16 within BK=128
            const int gp = ((s << 1) + half) ^ (l31 & 7);
            bf16x8 a[2], b[2];
            #pragma unroll
            for (int f = 0; f < 2; ++f) {
                const int rowA = (wy << 6) + (f << 5) + l31;
                const int rowB = (wx << 6) + (f << 5) + l31;
                a[f] = *reinterpret_cast<const bf16x8*>(ldsA + rowA * BK + (gp << 3));
                b[f] = *reinterpret_cast<const bf16x8*>(ldsB + rowB * BK + (gp << 3));
            }
            #pragma unroll
            for (int fy = 0; fy < 2; ++fy)
                #pragma unroll
                for (int fx = 0; fx < 2; ++fx)
                    acc[fy][fx] = __builtin_amdgcn_mfma_f32_32x32x16_bf16(
                        a[fy], b[fx], acc[fy][fx], 0, 0, 0);
        }
    }
    __syncthreads();                       // K-loop LDS reads done before E overwrite

    // Epilogue pass 1: exp, col partials, possum, E -> padded LDS.
    // C/D layout (m74/m101-verified): col = l31, row = (reg&3)+8*(reg>>2)+4*half.
    int ccol[2], lcol[2];
    #pragma unroll
    for (int fx = 0; fx < 2; ++fx) {
        ccol[fx] = (wx << 6) + (fx << 5) + l31;
        lcol[fx] = ldsLab[128 + ccol[fx]];
    }
    unsigned short* ePtr0 = ldsE + (half << 2) * ES + ccol[0];
    unsigned short* ePtr1 = ldsE + (half << 2) * ES + ccol[1];

    float cs[2] = {0.f, 0.f};
    float pp = 0.f;

    if (!isdiag) {                         // lean path (2016 blocks)
        #pragma unroll
        for (int fy = 0; fy < 2; ++fy) {
            const int rbase = (wy << 6) + (fy << 5) + (half << 2);
            int4 lr[4];
            #pragma unroll
            for (int g = 0; g < 4; ++g)
                lr[g] = *reinterpret_cast<const int4*>(&ldsLab[rbase + (g << 3)]);
            #pragma unroll
            for (int reg = 0; reg < 16; ++reg) {
                const int g = reg >> 2, idx = reg & 3;
                const int lrow = (idx == 0) ? lr[g].x : (idx == 1) ? lr[g].y
                               : (idx == 2) ? lr[g].z : lr[g].w;
                const int roff = (wy << 6) + (fy << 5) + idx + (g << 3); // +4*half in ePtr
                #pragma unroll
                for (int fx = 0; fx < 2; ++fx) {
                    const float a = acc[fy][fx][reg];
                    const float e = exp2f(a * LOG2E_T);
                    cs[fx] += e;
                    if (lcol[fx] == lrow) pp += a;
                    __hip_bfloat16 h = __float2bfloat16(e);
                    (fx ? ePtr1 : ePtr0)[roff * ES] = *reinterpret_cast<unsigned short*>(&h);
                }
            }
        }
    } else {                               // careful path (64 diag blocks)
        #pragma unroll
        for (int fy = 0; fy < 2; ++fy) {
            #pragma unroll
            for (int reg = 0; reg < 16; ++reg) {
                const int rloc = (reg & 3) + ((reg >> 2) << 3) + (half << 2);
                const int row_local = (wy << 6) + (fy << 5) + rloc;
                const int lrow = ldsLab[row_local];
                #pragma unroll
                for (int fx = 0; fx < 2; ++fx) {
                    const bool dband = (((wy << 1) + fy) == ((wx << 1) + fx));
                    const bool diag_el = dband && (l31 == rloc);
                    const float a = acc[fy][fx][reg];
                    float e = exp2f(a * LOG2E_T);
                    if (diag_el) e = 0.f;
                    cs[fx] += e;
                    if (lcol[fx] == lrow && !diag_el) pp += a;
                    __hip_bfloat16 h = __float2bfloat16(e);
                    ldsE[row_local * ES + ccol[fx]] = *reinterpret_cast<unsigned short*>(&h);
                }
            }
        }
    }
    const int anyhigh = (cs[0] > HI_THR) || (cs[1] > HI_THR);  // no false negatives
    #pragma unroll
    for (int fx = 0; fx < 2; ++fx) cs[fx] += __shfl_xor(cs[fx], 32);
    if (half == 0) {
        ldsCol[wy][ccol[0]] = cs[0];
        ldsCol[wy][ccol[1]] = cs[1];
    }
    #pragma unroll
    for (int off = 32; off > 0; off >>= 1) pp += __shfl_xor(pp, off);
    if (lane == 0) ldsP[wave] = pp;

    // Cold path (never taken for this data): relax-term bookkeeping.
    if (__any(anyhigh)) {
        #pragma unroll
        for (int fy = 0; fy < 2; ++fy) {
            #pragma unroll
            for (int reg = 0; reg < 16; ++reg) {
                const int rloc = (reg & 3) + ((reg >> 2) << 3) + (half << 2);
                const int row_local = (wy << 6) + (fy << 5) + rloc;
                const int lrow = ldsLab[row_local];
                #pragma unroll
                for (int fx = 0; fx < 2; ++fx) {
                    const bool dband = isdiag && (((wy << 1) + fy) == ((wx << 1) + fx));
                    const bool diag_el = dband && (l31 == rloc);
                    const float a = acc[fy][fx][reg];
                    if (a > 0.7f && lcol[fx] == lrow && !diag_el) {
                        const float e2 = exp2f(a * LOG2E_T);
                        atomicAdd(&hsum[I0 + row_local], e2);
                        atomicAdd(&nhighf[I0 + row_local], 1.f);
                        if (!isdiag) {
                            atomicAdd(&hsum[J0 + ccol[fx]], e2);
                            atomicAdd(&nhighf[J0 + ccol[fx]], 1.f);
                        }
                    }
                }
            }
        }
    }
    __syncthreads();                       // E complete (also ldsCol/ldsP)

    // Epilogue pass 2: row sums via MFMA (all 4 waves, rows [32w,+32)).
    {
        bf16x8 ones;
        #pragma unroll
        for (int j = 0; j < 8; ++j) ones[j] = (short)0x3F80;   // bf16 1.0
        f32x16 rs;
        #pragma unroll
        for (int e = 0; e < 16; ++e) rs[e] = 0.f;
        const int rE = (wave << 5) + l31;
        const unsigned short* rPtr = ldsE + rE * ES + (half << 3);
        #pragma unroll
        for (int kc = 0; kc < 8; ++kc) {
            bf16x8 bE = *reinterpret_cast<const bf16x8*>(rPtr + (kc << 4));
            rs = __builtin_amdgcn_mfma_f32_32x32x16_bf16(ones, bE, rs, 0, 0, 0);
        }
        if (half == 0) ldsRowF[rE] = rs[0];
    }
    __syncthreads();                       // ldsRowF + ldsCol ready

    if (tid < 128) {
        Q[(size_t)(bi * 64 + bj) * 128 + tid] = ldsRowF[tid];
    } else if (!isdiag) {
        const int c2 = tid - 128;
        Q[(size_t)(bj * 64 + bi) * 128 + c2] = ldsCol[0][c2] + ldsCol[1][c2];
    }
    if (tid == 0) {
        const float scale = isdiag ? 1.f : 2.f;
        atomicAdd(&scal[0], (ldsP[0] + ldsP[1] + ldsP[2] + ldsP[3]) * scale);
    }
}

// ---------------- Kernel 3: fused Q-reduce + finalize (64 blocks) ----------------
__global__ __launch_bounds__(256) void finalize_kernel(
    const float* __restrict__ Q, const float* __restrict__ hsum,
    const float* __restrict__ nhighf, const int* __restrict__ labels,
    float* __restrict__ scal, float* __restrict__ out) {
    const int g = blockIdx.x;
    const int tid = threadIdx.x;
    __shared__ int cnt[128];
    if (tid < 128) cnt[tid] = 0;
    __syncthreads();
    for (int i = tid; i < NB; i += 256)
        atomicAdd(&cnt[labels[i]], 1);
    const int r = tid & 127;
    const int sh = tid >> 7;
    const float* base = Q + (size_t)g * 64 * 128;
    float s = 0.f;
    #pragma unroll 8
    for (int i = 0; i < 32; ++i)
        s += base[(size_t)(sh * 32 + i) * 128 + r];
    __shared__ float red[256];
    red[tid] = s;
    __syncthreads();
    float SL = 0.f, RL = 0.f, NH = 0.f, NT = 0.f;
    if (tid < 128) {
        const float denom = red[tid] + red[tid + 128];
        const int i = (g << 7) + tid;
        const float np = (float)(cnt[labels[i]] - 1);
        SL = np * logf(denom + 1e-8f);
        const float h = hsum[i];
        if (h > 0.f) RL = logf(h + SELF_TERM);
        NH = nhighf[i];
    }
    if (g == 0 && tid < NCLSR) {
        const float nc = (float)cnt[tid];
        NT = nc * (nc - 1.f);
    }
    #pragma unroll
    for (int off = 32; off > 0; off >>= 1) {
        SL += __shfl_xor(SL, off); RL += __shfl_xor(RL, off);
        NH += __shfl_xor(NH, off); NT += __shfl_xor(NT, off);
    }
    __shared__ float part[4][4];
    if ((tid & 63) == 0) {
        int w = tid >> 6;
        part[w][0] = SL; part[w][1] = RL; part[w][2] = NH; part[w][3] = NT;
    }
    __syncthreads();
    if (tid == 0) {
        float sl = part[0][0] + part[1][0] + part[2][0] + part[3][0];
        float rl = part[0][1] + part[1][1] + part[2][1] + part[3][1];
        float nh = part[0][2] + part[1][2] + part[2][2] + part[3][2];
        float nt = part[0][3] + part[1][3] + part[2][3] + part[3][3];
        atomicAdd(&scal[1], sl);
        atomicAdd(&scal[2], rl);
        atomicAdd(&scal[3], nh);
        if (g == 0) atomicAdd(&scal[4], nt);
        __threadfence();
        const int ticket = atomicAdd((int*)(scal + 5), 1);
        if (ticket == 63) {
            const float SLt = atomicAdd(&scal[1], 0.f);
            const float RLt = atomicAdd(&scal[2], 0.f);
            const float NHt = atomicAdd(&scal[3], 0.f);
            const float NTt = atomicAdd(&scal[4], 0.f);
            const float pos = atomicAdd(&scal[0], 0.f) * INV_T;
            const float scl   = (NTt > 0.f) ? (SLt - pos) / NTt : 0.f;
            const float relax = (NHt > 0.f) ? RLt / NHt : 0.f;
            out[0] = scl + relax;
        }
    }
}

extern "C" void kernel_launch(void* const* d_in, const int* in_sizes, int n_in,
                              void* d_out, int out_size, void* d_ws, size_t ws_size,
                              hipStream_t stream) {
    const float* feat  = (const float*)d_in[0];
    const int* labels  = (const int*)d_in[1];
    float* out = (float*)d_out;

    char* ws = (char*)d_ws;
    unsigned short* fb = (unsigned short*)ws;                                // 4 MB
    float* Q      = (float*)(ws + (size_t)NB * ND * sizeof(unsigned short)); // 2 MB
    float* hsum   = Q + 64 * 64 * 128;
    float* nhighf = hsum + NB;
    float* scal   = nhighf + NB;          // 6 floats: possum,SL,RL,NH,NT,done

    normalize_kernel<<<NB / 4, 256, 0, stream>>>(feat, fb, hsum, nhighf, scal);
    sim_kernel<<<2080, 256, 0, stream>>>(fb, labels, Q, hsum, nhighf, scal);
    finalize_kernel<<<64, 256, 0, stream>>>(Q, hsum, nhighf, labels, scal, out);
}

// Round 17
// 116.503 us; speedup vs baseline: 1.0810x; 1.0161x over previous
//
#include <hip/hip_runtime.h>
#include <hip/hip_bf16.h>
#include <math.h>

typedef short bf16x8 __attribute__((ext_vector_type(8)));   // 8 bf16 in 4 VGPRs
typedef float f32x16 __attribute__((ext_vector_type(16)));  // 32x32 MFMA acc

#define NB 8192
#define ND 256
#define NCLSR 100         // label values 0..99
#define BK 64             // K-chunk staged in LDS per iteration
#define ES 136            // padded E row stride (bf16): 272 B -> 16B-aligned rows
#define INV_T 20.0f       // 1/TEMPERATURE
#define LOG2E_T 28.853900817779268f   // 20*log2(e): exp(20x) = 2^(x*this)
#define HI_THR 1.2026042e6f           // exp(14)
#define SELF_TERM 4.85165195e8f       // exp(20)

// scal[] layout: [0]=possum [1]=SL [2]=RL [3]=NH [4]=NT [5]=done-counter(int)

// ---------------- Kernel 1: row L2-normalize -> bf16 copy; zero accumulators --------
__global__ __launch_bounds__(256) void normalize_kernel(
    const float* __restrict__ feat, unsigned short* __restrict__ fb,
    float* __restrict__ hsum, float* __restrict__ nhighf,
    float* __restrict__ scal) {
    const int wave = threadIdx.x >> 6;
    const int lane = threadIdx.x & 63;
    const int row  = blockIdx.x * 4 + wave;
    float4 v = reinterpret_cast<const float4*>(feat + (size_t)row * ND)[lane];
    float ss = v.x * v.x + v.y * v.y + v.z * v.z + v.w * v.w;
    #pragma unroll
    for (int off = 32; off > 0; off >>= 1) ss += __shfl_xor(ss, off);
    const float inv = rsqrtf(ss);
    ushort4 o;
    __hip_bfloat16 h0 = __float2bfloat16(v.x * inv); o.x = *reinterpret_cast<unsigned short*>(&h0);
    __hip_bfloat16 h1 = __float2bfloat16(v.y * inv); o.y = *reinterpret_cast<unsigned short*>(&h1);
    __hip_bfloat16 h2 = __float2bfloat16(v.z * inv); o.z = *reinterpret_cast<unsigned short*>(&h2);
    __hip_bfloat16 h3 = __float2bfloat16(v.w * inv); o.w = *reinterpret_cast<unsigned short*>(&h3);
    reinterpret_cast<ushort4*>(fb + (size_t)row * ND)[lane] = o;
    if (blockIdx.x < 32) {
        const int i = (blockIdx.x << 8) + threadIdx.x;
        hsum[i] = 0.f;
        nhighf[i] = 0.f;
    } else if (blockIdx.x == 32 && threadIdx.x < 6) {
        scal[threadIdx.x] = 0.f;           // int 0 == float 0 bit pattern
    }
}

// ---------------- Kernel 2: TRIANGULAR sim tiles, 4 waves x (64x64) ----------
// R17 = R14 exactly (session best: sim 47.4 us, total 117.66 us).
// 256 threads = 4 waves, wave tile 64x64 as 2x2 frags of
// v_mfma_f32_32x32x16_bf16. BK=64 staging via global_load_lds width-16,
// XOR-granule swizzle in the GLOBAL address. Padded-E (ES=136) MFMA ones-trick
// for row sums; Q mirror slots (row sums -> [bi][bj], col sums -> [bj][bi]);
// lean/diag split; possum via one atomic per block.
// Config is the measured local optimum of resident-blocks x barrier-overlap:
// 37.9 KB LDS + 140 unified regs -> 3 blocks/CU. R13 (cooperative, 1 block/CU),
// R15 (dual-MFMA, 252 regs), R16 (BK=128, 68.6 KB LDS) all regressed by
// breaking exactly this.
__global__ __launch_bounds__(256, 2) void sim_kernel(
    const unsigned short* __restrict__ fb, const int* __restrict__ labels,
    float* __restrict__ Q, float* __restrict__ hsum,
    float* __restrict__ nhighf, float* __restrict__ scal) {
    __shared__ __align__(16) unsigned short ldsU[128 * ES]; // 34816 B: A|B staging, E overlay
    __shared__ float ldsCol[2][128];       // [wy][local col] partial col sums
    __shared__ float ldsRowF[128];         // full row sums (MFMA ones-trick)
    __shared__ int   ldsLab[256];          // [0..127]=row labels, [128..255]=col labels
    __shared__ float ldsP[4];              // per-wave possum partials
    unsigned short* ldsA = ldsU;
    unsigned short* ldsB = ldsU + 128 * BK;
    unsigned short* ldsE = ldsU;           // 128 x ES bf16 overlay

    // triangular decode: t -> (bi, bj), bi >= bj  (validated R5-R16)
    const int t = blockIdx.x;
    int bi = (int)((sqrtf((float)(8 * t + 1)) - 1.0f) * 0.5f);
    while ((bi + 1) * (bi + 2) / 2 <= t) ++bi;
    while (bi * (bi + 1) / 2 > t) --bi;
    const int bj = t - bi * (bi + 1) / 2;
    const int I0 = bi << 7;
    const int J0 = bj << 7;
    const bool isdiag = (bi == bj);

    const int tid  = threadIdx.x;
    const int wave = tid >> 6;             // 0..3
    const int lane = tid & 63;
    const int wy = wave >> 1;              // 0..1 : row half (64 rows)
    const int wx = wave & 1;               // 0..1 : col half (64 cols)
    const int l31  = lane & 31;
    const int half = lane >> 5;

    if (tid < 128) ldsLab[tid] = labels[I0 + tid];
    else           ldsLab[tid] = labels[J0 + tid - 128];

    // staging: wave stages rows [32w,+32); chunk c: Lg=(c<<6)+lane,
    // row_loc = 32w + (Lg>>3), granule g = (Lg&7)^((Lg>>3)&7)  (R4-validated)
    int offRC[4];
    #pragma unroll
    for (int c = 0; c < 4; ++c) {
        const int Lg = (c << 6) + lane;
        const int row_loc = (wave << 5) + (Lg >> 3);
        const int g = (Lg & 7) ^ ((Lg >> 3) & 7);
        offRC[c] = row_loc * ND + (g << 3);
    }
    const unsigned short* baseA = fb + (size_t)I0 * ND;
    const unsigned short* baseB = fb + (size_t)J0 * ND;

    f32x16 acc[2][2];
    #pragma unroll
    for (int fy = 0; fy < 2; ++fy)
        #pragma unroll
        for (int fx = 0; fx < 2; ++fx)
            #pragma unroll
            for (int e = 0; e < 16; ++e) acc[fy][fx][e] = 0.f;

    for (int kk = 0; kk < ND; kk += BK) {
        __syncthreads();                   // protect LDS from prior-iter readers
        #pragma unroll
        for (int c = 0; c < 4; ++c) {
            __builtin_amdgcn_global_load_lds(
                (const __attribute__((address_space(1))) void*)(baseA + offRC[c] + kk),
                (__attribute__((address_space(3))) void*)(ldsA + (wave << 11) + (c << 9)),
                16, 0, 0);
            __builtin_amdgcn_global_load_lds(
                (const __attribute__((address_space(1))) void*)(baseB + offRC[c] + kk),
                (__attribute__((address_space(3))) void*)(ldsB + (wave << 11) + (c << 9)),
                16, 0, 0);
        }
        __syncthreads();                   // staging visible

        #pragma unroll
        for (int s = 0; s < 4; ++s) {      // four k-steps of 16 within BK=64
            const int gp = ((s << 1) + half) ^ (l31 & 7);
            bf16x8 a[2], b[2];
            #pragma unroll
            for (int f = 0; f < 2; ++f) {
                const int rowA = (wy << 6) + (f << 5) + l31;
                const int rowB = (wx << 6) + (f << 5) + l31;
                a[f] = *reinterpret_cast<const bf16x8*>(ldsA + rowA * BK + (gp << 3));
                b[f] = *reinterpret_cast<const bf16x8*>(ldsB + rowB * BK + (gp << 3));
            }
            #pragma unroll
            for (int fy = 0; fy < 2; ++fy)
                #pragma unroll
                for (int fx = 0; fx < 2; ++fx)
                    acc[fy][fx] = __builtin_amdgcn_mfma_f32_32x32x16_bf16(
                        a[fy], b[fx], acc[fy][fx], 0, 0, 0);
        }
    }
    __syncthreads();                       // K-loop LDS reads done before E overwrite

    // Epilogue pass 1: exp, col partials, possum, E -> padded LDS.
    // C/D layout (m74/m101-verified): col = l31, row = (reg&3)+8*(reg>>2)+4*half.
    int ccol[2], lcol[2];
    #pragma unroll
    for (int fx = 0; fx < 2; ++fx) {
        ccol[fx] = (wx << 6) + (fx << 5) + l31;
        lcol[fx] = ldsLab[128 + ccol[fx]];
    }
    unsigned short* ePtr0 = ldsE + (half << 2) * ES + ccol[0];
    unsigned short* ePtr1 = ldsE + (half << 2) * ES + ccol[1];

    float cs[2] = {0.f, 0.f};
    float pp = 0.f;

    if (!isdiag) {                         // lean path (2016 blocks)
        #pragma unroll
        for (int fy = 0; fy < 2; ++fy) {
            const int rbase = (wy << 6) + (fy << 5) + (half << 2);
            int4 lr[4];
            #pragma unroll
            for (int g = 0; g < 4; ++g)
                lr[g] = *reinterpret_cast<const int4*>(&ldsLab[rbase + (g << 3)]);
            #pragma unroll
            for (int reg = 0; reg < 16; ++reg) {
                const int g = reg >> 2, idx = reg & 3;
                const int lrow = (idx == 0) ? lr[g].x : (idx == 1) ? lr[g].y
                               : (idx == 2) ? lr[g].z : lr[g].w;
                const int roff = (wy << 6) + (fy << 5) + idx + (g << 3); // +4*half in ePtr
                #pragma unroll
                for (int fx = 0; fx < 2; ++fx) {
                    const float a = acc[fy][fx][reg];
                    const float e = exp2f(a * LOG2E_T);
                    cs[fx] += e;
                    if (lcol[fx] == lrow) pp += a;
                    __hip_bfloat16 h = __float2bfloat16(e);
                    (fx ? ePtr1 : ePtr0)[roff * ES] = *reinterpret_cast<unsigned short*>(&h);
                }
            }
        }
    } else {                               // careful path (64 diag blocks)
        #pragma unroll
        for (int fy = 0; fy < 2; ++fy) {
            #pragma unroll
            for (int reg = 0; reg < 16; ++reg) {
                const int rloc = (reg & 3) + ((reg >> 2) << 3) + (half << 2);
                const int row_local = (wy << 6) + (fy << 5) + rloc;
                const int lrow = ldsLab[row_local];
                #pragma unroll
                for (int fx = 0; fx < 2; ++fx) {
                    const bool dband = (((wy << 1) + fy) == ((wx << 1) + fx));
                    const bool diag_el = dband && (l31 == rloc);
                    const float a = acc[fy][fx][reg];
                    float e = exp2f(a * LOG2E_T);
                    if (diag_el) e = 0.f;
                    cs[fx] += e;
                    if (lcol[fx] == lrow && !diag_el) pp += a;
                    __hip_bfloat16 h = __float2bfloat16(e);
                    ldsE[row_local * ES + ccol[fx]] = *reinterpret_cast<unsigned short*>(&h);
                }
            }
        }
    }
    const int anyhigh = (cs[0] > HI_THR) || (cs[1] > HI_THR);  // no false negatives
    #pragma unroll
    for (int fx = 0; fx < 2; ++fx) cs[fx] += __shfl_xor(cs[fx], 32);
    if (half == 0) {
        ldsCol[wy][ccol[0]] = cs[0];
        ldsCol[wy][ccol[1]] = cs[1];
    }
    #pragma unroll
    for (int off = 32; off > 0; off >>= 1) pp += __shfl_xor(pp, off);
    if (lane == 0) ldsP[wave] = pp;

    // Cold path (never taken for this data): relax-term bookkeeping.
    if (__any(anyhigh)) {
        #pragma unroll
        for (int fy = 0; fy < 2; ++fy) {
            #pragma unroll
            for (int reg = 0; reg < 16; ++reg) {
                const int rloc = (reg & 3) + ((reg >> 2) << 3) + (half << 2);
                const int row_local = (wy << 6) + (fy << 5) + rloc;
                const int lrow = ldsLab[row_local];
                #pragma unroll
                for (int fx = 0; fx < 2; ++fx) {
                    const bool dband = isdiag && (((wy << 1) + fy) == ((wx << 1) + fx));
                    const bool diag_el = dband && (l31 == rloc);
                    const float a = acc[fy][fx][reg];
                    if (a > 0.7f && lcol[fx] == lrow && !diag_el) {
                        const float e2 = exp2f(a * LOG2E_T);
                        atomicAdd(&hsum[I0 + row_local], e2);
                        atomicAdd(&nhighf[I0 + row_local], 1.f);
                        if (!isdiag) {
                            atomicAdd(&hsum[J0 + ccol[fx]], e2);
                            atomicAdd(&nhighf[J0 + ccol[fx]], 1.f);
                        }
                    }
                }
            }
        }
    }
    __syncthreads();                       // E complete (also ldsCol/ldsP)

    // Epilogue pass 2: row sums via MFMA (all 4 waves, rows [32w,+32)).
    // D = ones x E_B: B-frag lane n holds E[32w+n][k-chunk] -> D[.][n] =
    // rowsum(E[32w+n]), replicated across regs.
    {
        bf16x8 ones;
        #pragma unroll
        for (int j = 0; j < 8; ++j) ones[j] = (short)0x3F80;   // bf16 1.0
        f32x16 rs;
        #pragma unroll
        for (int e = 0; e < 16; ++e) rs[e] = 0.f;
        const int rE = (wave << 5) + l31;
        const unsigned short* rPtr = ldsE + rE * ES + (half << 3);
        #pragma unroll
        for (int kc = 0; kc < 8; ++kc) {
            bf16x8 bE = *reinterpret_cast<const bf16x8*>(rPtr + (kc << 4));
            rs = __builtin_amdgcn_mfma_f32_32x32x16_bf16(ones, bE, rs, 0, 0, 0);
        }
        if (half == 0) ldsRowF[rE] = rs[0];
    }
    __syncthreads();                       // ldsRowF + ldsCol ready

    if (tid < 128) {
        Q[(size_t)(bi * 64 + bj) * 128 + tid] = ldsRowF[tid];
    } else if (!isdiag) {
        const int c2 = tid - 128;
        Q[(size_t)(bj * 64 + bi) * 128 + c2] = ldsCol[0][c2] + ldsCol[1][c2];
    }
    if (tid == 0) {
        const float scale = isdiag ? 1.f : 2.f;
        atomicAdd(&scal[0], (ldsP[0] + ldsP[1] + ldsP[2] + ldsP[3]) * scale);
    }
}

// ---------------- Kernel 3: fused Q-reduce + finalize (64 blocks) ----------------
__global__ __launch_bounds__(256) void finalize_kernel(
    const float* __restrict__ Q, const float* __restrict__ hsum,
    const float* __restrict__ nhighf, const int* __restrict__ labels,
    float* __restrict__ scal, float* __restrict__ out) {
    const int g = blockIdx.x;
    const int tid = threadIdx.x;
    __shared__ int cnt[128];
    if (tid < 128) cnt[tid] = 0;
    __syncthreads();
    for (int i = tid; i < NB; i += 256)
        atomicAdd(&cnt[labels[i]], 1);
    const int r = tid & 127;
    const int sh = tid >> 7;
    const float* base = Q + (size_t)g * 64 * 128;
    float s = 0.f;
    #pragma unroll 8
    for (int i = 0; i < 32; ++i)
        s += base[(size_t)(sh * 32 + i) * 128 + r];
    __shared__ float red[256];
    red[tid] = s;
    __syncthreads();
    float SL = 0.f, RL = 0.f, NH = 0.f, NT = 0.f;
    if (tid < 128) {
        const float denom = red[tid] + red[tid + 128];
        const int i = (g << 7) + tid;
        const float np = (float)(cnt[labels[i]] - 1);
        SL = np * logf(denom + 1e-8f);
        const float h = hsum[i];
        if (h > 0.f) RL = logf(h + SELF_TERM);
        NH = nhighf[i];
    }
    if (g == 0 && tid < NCLSR) {
        const float nc = (float)cnt[tid];
        NT = nc * (nc - 1.f);
    }
    #pragma unroll
    for (int off = 32; off > 0; off >>= 1) {
        SL += __shfl_xor(SL, off); RL += __shfl_xor(RL, off);
        NH += __shfl_xor(NH, off); NT += __shfl_xor(NT, off);
    }
    __shared__ float part[4][4];
    if ((tid & 63) == 0) {
        int w = tid >> 6;
        part[w][0] = SL; part[w][1] = RL; part[w][2] = NH; part[w][3] = NT;
    }
    __syncthreads();
    if (tid == 0) {
        float sl = part[0][0] + part[1][0] + part[2][0] + part[3][0];
        float rl = part[0][1] + part[1][1] + part[2][1] + part[3][1];
        float nh = part[0][2] + part[1][2] + part[2][2] + part[3][2];
        float nt = part[0][3] + part[1][3] + part[2][3] + part[3][3];
        atomicAdd(&scal[1], sl);
        atomicAdd(&scal[2], rl);
        atomicAdd(&scal[3], nh);
        if (g == 0) atomicAdd(&scal[4], nt);
        __threadfence();
        const int ticket = atomicAdd((int*)(scal + 5), 1);
        if (ticket == 63) {
            const float SLt = atomicAdd(&scal[1], 0.f);
            const float RLt = atomicAdd(&scal[2], 0.f);
            const float NHt = atomicAdd(&scal[3], 0.f);
            const float NTt = atomicAdd(&scal[4], 0.f);
            const float pos = atomicAdd(&scal[0], 0.f) * INV_T;
            const float scl   = (NTt > 0.f) ? (SLt - pos) / NTt : 0.f;
            const float relax = (NHt > 0.f) ? RLt / NHt : 0.f;
            out[0] = scl + relax;
        }
    }
}

extern "C" void kernel_launch(void* const* d_in, const int* in_sizes, int n_in,
                              void* d_out, int out_size, void* d_ws, size_t ws_size,
                              hipStream_t stream) {
    const float* feat  = (const float*)d_in[0];
    const int* labels  = (const int*)d_in[1];
    float* out = (float*)d_out;

    char* ws = (char*)d_ws;
    unsigned short* fb = (unsigned short*)ws;                                // 4 MB
    float* Q      = (float*)(ws + (size_t)NB * ND * sizeof(unsigned short)); // 2 MB
    float* hsum   = Q + 64 * 64 * 128;
    float* nhighf = hsum + NB;
    float* scal   = nhighf + NB;          // 6 floats: possum,SL,RL,NH,NT,done

    normalize_kernel<<<NB / 4, 256, 0, stream>>>(feat, fb, hsum, nhighf, scal);
    sim_kernel<<<2080, 256, 0, stream>>>(fb, labels, Q, hsum, nhighf, scal);
    finalize_kernel<<<64, 256, 0, stream>>>(Q, hsum, nhighf, labels, scal, out);
}